// Round 6
// baseline (768.773 us; speedup 1.0000x reference)
//
#include <hip/hip_runtime.h>

#define N_NODES 50000
#define N_EDGES 800000
#define CAP 48
#define PB_BLOCKS 2560
#define BIN_NODES 128
#define NBINS 391          // ceil(50000 / 128)
#define BINCAP 4096        // mean 2046 edges/bin, +45 sigma slack
// IN_F = 64, OUT_F = 64, EDGE_F = 16, d_in1 = 144
// NOTE: harness passes ALL integer inputs as int32 — edge_index is int32[2*E],
// src = ei[e], dst = ei[E+e].
// NOTE (round 3): hipLaunchCooperativeKernel inside kernel_launch broke the
// harness (graph capture) — container failed twice. DO NOT use coop launch.
// NOTE (round 5): direct per-edge scattered slot writes drain at ~740 GB/s
// (partial-line writebacks across 8 non-coherent L2s) — 111 us. Hence the
// two-level binned build below: all bucket writes coalesced.

#define FMA16(acc, ep, wreg)                                                 \
    {                                                                        \
        float4 _e0 = (ep)[0], _e1 = (ep)[1], _e2 = (ep)[2], _e3 = (ep)[3];   \
        acc += _e0.x * wreg[0];  acc += _e0.y * wreg[1];                     \
        acc += _e0.z * wreg[2];  acc += _e0.w * wreg[3];                     \
        acc += _e1.x * wreg[4];  acc += _e1.y * wreg[5];                     \
        acc += _e1.z * wreg[6];  acc += _e1.w * wreg[7];                     \
        acc += _e2.x * wreg[8];  acc += _e2.y * wreg[9];                     \
        acc += _e2.z * wreg[10]; acc += _e2.w * wreg[11];                    \
        acc += _e3.x * wreg[12]; acc += _e3.y * wreg[13];                    \
        acc += _e3.z * wreg[14]; acc += _e3.w * wreg[15];                    \
    }

// ---------------------------------------------------------------------------
// prebuild_kernel: EVERY block does
//   (1) bin chunk (XCD-sharded): edges with (dst>>7)%8 == blockIdx%8 are
//       appended to coarse bin dst>>7 as packed ((dst&127)<<20 | e).
//       Sequential appends -> bin tail lines stay hot in ONE XCD's L2 ->
//       coalesced writebacks (~3.2 MB total instead of ~50 MB scattered).
//   (2) pre chunk: xa = x @ W1[0:64,:], xb = x @ W1[64:128,:]
// bcnt/ocnt must be zeroed before launch (tiny memsetAsync).
// ---------------------------------------------------------------------------
__global__ __launch_bounds__(256) void prebuild_kernel(
    const float* __restrict__ x, const float* __restrict__ W1,
    float* __restrict__ xa, float* __restrict__ xb,
    const int* __restrict__ ei, unsigned* __restrict__ bcnt,
    unsigned* __restrict__ ocnt, unsigned* __restrict__ bins,
    unsigned* __restrict__ oflow)
{
    const int tid = threadIdx.x;
    const int bid = blockIdx.x;

    // ---- bin part: shard s handles bins with bin%8 == s ----
    {
        const int s  = bid & 7;
        const int wb = bid >> 3;                       // 0..319 within shard
        for (int e = wb * 256 + tid; e < N_EDGES; e += (PB_BLOCKS / 8) * 256) {
            const int d = ei[N_EDGES + e];
            const int bin = d >> 7;
            if ((bin & 7) == s) {
                const unsigned pos = atomicAdd(&bcnt[bin], 1u);
                if (pos < BINCAP) {
                    bins[(size_t)bin * BINCAP + pos] =
                        ((unsigned)(d & 127) << 20) | (unsigned)e;
                } else {
                    const unsigned oi = atomicAdd(ocnt, 1u);
                    oflow[oi] = (unsigned)e;
                }
            }
        }
    }

    // ---- pre part: wave per (node-subset, product) ----
    const int w = tid >> 6;
    const int j = tid & 63;
    const int gw = bid * 4 + w;
    const int p = gw & 1;              // 0 -> xa, 1 -> xb
    const int pair = gw >> 1;
    const int npair = PB_BLOCKS * 2;   // 5120

    float wc[64];
#pragma unroll
    for (int k = 0; k < 64; ++k) wc[k] = W1[(p * 64 + k) * 64 + j];
    float* __restrict__ outp = p ? xb : xa;
    for (int i = pair; i < N_NODES; i += npair) {
        const float4* xr = (const float4*)&x[(size_t)i * 64];
        float acc = 0.f;
#pragma unroll
        for (int k4 = 0; k4 < 16; ++k4) {
            float4 xv = xr[k4];
            acc += xv.x * wc[k4 * 4 + 0];
            acc += xv.y * wc[k4 * 4 + 1];
            acc += xv.z * wc[k4 * 4 + 2];
            acc += xv.w * wc[k4 * 4 + 3];
        }
        outp[(size_t)i * 64 + j] = acc;
    }
}

// ---------------------------------------------------------------------------
// bucketize_kernel: one block per coarse bin. Builds the per-node bucket
// table in LDS (LDS atomics), then writes cnt + slot fully COALESCED.
// Also writes cnt for every node -> no 50k-entry memset needed.
// ---------------------------------------------------------------------------
__global__ __launch_bounds__(256) void bucketize_kernel(
    const unsigned* __restrict__ bins, const unsigned* __restrict__ bcnt,
    unsigned* __restrict__ cnt, unsigned* __restrict__ slot,
    unsigned* __restrict__ ocnt, unsigned* __restrict__ oflow)
{
    __shared__ unsigned lcnt[BIN_NODES];
    __shared__ unsigned lslot[BIN_NODES * CAP];     // 24 KB

    const int tid = threadIdx.x;
    const int bin = blockIdx.x;

    for (int i = tid; i < BIN_NODES; i += 256) lcnt[i] = 0;
    __syncthreads();

    const unsigned bc = bcnt[bin];
    const int ecount = bc < BINCAP ? (int)bc : BINCAP;
    const unsigned* bp = bins + (size_t)bin * BINCAP;
    for (int i = tid; i < ecount; i += 256) {
        const unsigned v = bp[i];
        const unsigned ld = v >> 20;
        const unsigned pos = atomicAdd(&lcnt[ld], 1u);
        if (pos < CAP) {
            lslot[ld * CAP + pos] = v & 0xFFFFFu;
        } else {
            const unsigned oi = atomicAdd(ocnt, 1u);
            oflow[oi] = v & 0xFFFFFu;
        }
    }
    __syncthreads();

    const int nbase = bin * BIN_NODES;
    if (tid < BIN_NODES) {
        const int n = nbase + tid;
        if (n < N_NODES) {
            const unsigned c = lcnt[tid];
            cnt[n] = c < CAP ? c : CAP;
        }
    }
    for (int idx = tid; idx < BIN_NODES * CAP; idx += 256) {
        const int n = nbase + idx / CAP;
        if (n < N_NODES) slot[(size_t)nbase * CAP + idx] = lslot[idx];
    }
}

// ---------------------------------------------------------------------------
// nodefused_kernel: one wave per dst node.  (UNCHANGED from round 5)
//   hacc = sum_e relu(xa[src]+xb[n]+ea@W1c+b1)    (aggregation)
//   out[n] = hacc @ W2 + dcap*b2                  (W2 hoisted out of seg-sum)
// ---------------------------------------------------------------------------
__global__ __launch_bounds__(256) void nodefused_kernel(
    const float* __restrict__ xa, const float* __restrict__ xb,
    const float* __restrict__ ea, const unsigned* __restrict__ slot,
    const int* __restrict__ ei, const unsigned* __restrict__ cnt,
    const float* __restrict__ W1, const float* __restrict__ b1,
    const float* __restrict__ W2, const float* __restrict__ b2,
    float* __restrict__ out)
{
    __shared__ __align__(16) float sea[4][CAP * 16];   // 12 KB / block

    const int w = threadIdx.x >> 6;
    const int j = threadIdx.x & 63;
    const int n = blockIdx.x * 4 + w;

    float w1c[16];
#pragma unroll
    for (int k = 0; k < 16; ++k) w1c[k] = W1[(128 + k) * 64 + j];
    const float b1j = b1[j];
    const float b2j = b2[j];

    const int deg = (int)cnt[n];
    const int dcap = deg < CAP ? deg : CAP;

    int ev = 0, sv = 0;
    if (j < dcap) {
        ev = (int)slot[(size_t)n * CAP + j];
        sv = ei[ev];
    }

    const float base = xb[(size_t)n * 64 + j] + b1j;

    float hacc = 0.f;
    if (dcap > 0) {
        const int sub = j >> 2;
        const int q   = j & 3;

        for (int b0 = 0; b0 < dcap; b0 += 16) {
            {
                int ii = b0 + sub;
                const int ic = ii < dcap ? ii : dcap - 1;
                const unsigned eid = (unsigned)__shfl(ev, ic);
                float4 v = *(const float4*)(ea + (size_t)eid * 16 + q * 4);
                *(float4*)&sea[w][ic * 16 + q * 4] = v;
            }
            float xv[16];
#pragma unroll
            for (int t = 0; t < 16; ++t) {
                int ii = b0 + t;
                const int ic = ii < dcap ? ii : dcap - 1;
                const unsigned ss =
                    (unsigned)__builtin_amdgcn_readlane(sv, ic);
                xv[t] = xa[(size_t)ss * 64 + j];
            }
#pragma unroll
            for (int t = 0; t < 16; ++t) {
                const int ii = b0 + t;
                if (ii < dcap) {
                    const float4* ep = (const float4*)&sea[w][ii * 16];
                    float acc = base + xv[t];
                    FMA16(acc, ep, w1c);
                    hacc += fmaxf(acc, 0.f);
                }
            }
        }
    }

    sea[w][j] = hacc;
    float msg = (float)dcap * b2j;
#pragma unroll
    for (int k4 = 0; k4 < 16; ++k4) {
        float4 hv = *(const float4*)&sea[w][k4 * 4];
        msg += hv.x * W2[(k4 * 4 + 0) * 64 + j];
        msg += hv.y * W2[(k4 * 4 + 1) * 64 + j];
        msg += hv.z * W2[(k4 * 4 + 2) * 64 + j];
        msg += hv.w * W2[(k4 * 4 + 3) * 64 + j];
    }
    out[(size_t)n * 64 + j] = msg;
}

// ---------------------------------------------------------------------------
// overflow_kernel: correctness net (expected 0 edges). Runs AFTER nodefused.
// ---------------------------------------------------------------------------
__global__ __launch_bounds__(256) void overflow_kernel(
    const float* __restrict__ xa, const float* __restrict__ xb,
    const int* __restrict__ ei, const float* __restrict__ ea,
    const float* __restrict__ W1, const float* __restrict__ b1,
    const float* __restrict__ W2, const float* __restrict__ b2,
    const unsigned* __restrict__ ocnt, const unsigned* __restrict__ oflow,
    float* __restrict__ out)
{
    const unsigned oc = *ocnt;
    if (oc == 0) return;
    const int w = threadIdx.x >> 6;
    const int j = threadIdx.x & 63;
    unsigned idx = blockIdx.x * 4 + w;
    const unsigned stride = gridDim.x * 4;
    for (; idx < oc; idx += stride) {
        const int e = (int)oflow[idx];
        const int s = ei[e];
        const int dd = ei[N_EDGES + e];
        float acc = xa[(size_t)s * 64 + j] + xb[(size_t)dd * 64 + j] + b1[j];
        for (int k = 0; k < 16; ++k)
            acc += ea[(size_t)e * 16 + k] * W1[(128 + k) * 64 + j];
        const float h = fmaxf(acc, 0.f);
        float msg = b2[j];
        for (int k = 0; k < 64; ++k) msg += __shfl(h, k) * W2[k * 64 + j];
        unsafeAtomicAdd(&out[(size_t)dd * 64 + j], msg);
    }
}

// ---------------------------------------------------------------------------
// OLD PATH kernels (ws too small for bucketed pipeline)
// ---------------------------------------------------------------------------
__global__ __launch_bounds__(256) void pre_kernel(
    const float* __restrict__ x, const float* __restrict__ W1,
    float* __restrict__ xa, float* __restrict__ xb)
{
    const int w = threadIdx.x >> 6;
    const int j = threadIdx.x & 63;
    const int gw = blockIdx.x * 4 + w;
    const int p = gw & 1;
    const int pair = gw >> 1;
    const int npair = (gridDim.x * 4) >> 1;

    float wc[64];
#pragma unroll
    for (int k = 0; k < 64; ++k) wc[k] = W1[(p * 64 + k) * 64 + j];
    float* __restrict__ outp = p ? xb : xa;
    for (int i = pair; i < N_NODES; i += npair) {
        const float4* xr = (const float4*)&x[(size_t)i * 64];
        float acc = 0.f;
#pragma unroll
        for (int k4 = 0; k4 < 16; ++k4) {
            float4 xv = xr[k4];
            acc += xv.x * wc[k4 * 4 + 0];
            acc += xv.y * wc[k4 * 4 + 1];
            acc += xv.z * wc[k4 * 4 + 2];
            acc += xv.w * wc[k4 * 4 + 3];
        }
        outp[(size_t)i * 64 + j] = acc;
    }
}

__global__ __launch_bounds__(256) void edge_kernel(
    const float* __restrict__ xa, const float* __restrict__ xb,
    const int* __restrict__ ei,
    const float* __restrict__ edge_attr,
    const float* __restrict__ W1, const float* __restrict__ b1,
    const float* __restrict__ W2, const float* __restrict__ b2,
    float* __restrict__ out)
{
    __shared__ __align__(16) float eas[4][256];
    __shared__ __align__(16) float hs[4][16][64];

    const int w = threadIdx.x >> 6;
    const int j = threadIdx.x & 63;
    const int wt = blockIdx.x * 4 + w;
    const long eb = (long)wt * 16;

    float w1c[16];
    float w2c[64];
#pragma unroll
    for (int k = 0; k < 16; ++k) w1c[k] = W1[(128 + k) * 64 + j];
#pragma unroll
    for (int k = 0; k < 64; ++k) w2c[k] = W2[k * 64 + j];
    const float b1j = b1[j];
    const float b2j = b2[j];

    int idxv = 0;
    if (j < 16)       idxv = ei[eb + j];
    else if (j < 32)  idxv = ei[(long)N_EDGES + eb + (j - 16)];

    {
        float4 ev = *(const float4*)&edge_attr[eb * 16 + j * 4];
        *(float4*)&eas[w][j * 4] = ev;
    }

#pragma unroll 4
    for (int e = 0; e < 16; ++e) {
        const int s  = __shfl(idxv, e);
        const int dd = __shfl(idxv, 16 + e);

        float acc = xa[(long)s * 64 + j] + xb[(long)dd * 64 + j] + b1j;
#pragma unroll
        for (int k4 = 0; k4 < 4; ++k4) {
            float4 ev = *(const float4*)&eas[w][e * 16 + k4 * 4];
            acc += ev.x * w1c[k4 * 4 + 0];
            acc += ev.y * w1c[k4 * 4 + 1];
            acc += ev.z * w1c[k4 * 4 + 2];
            acc += ev.w * w1c[k4 * 4 + 3];
        }
        const float h = fmaxf(acc, 0.f);
        hs[w][e][j] = h;

        float msg = b2j;
#pragma unroll
        for (int k4 = 0; k4 < 16; ++k4) {
            float4 hv = *(const float4*)&hs[w][e][k4 * 4];
            msg += hv.x * w2c[k4 * 4 + 0];
            msg += hv.y * w2c[k4 * 4 + 1];
            msg += hv.z * w2c[k4 * 4 + 2];
            msg += hv.w * w2c[k4 * 4 + 3];
        }
        unsafeAtomicAdd(&out[(long)dd * 64 + j], msg);
    }
}

__global__ __launch_bounds__(256) void fallback_kernel(
    const float* __restrict__ x, const int* __restrict__ ei,
    const float* __restrict__ edge_attr,
    const float* __restrict__ W1, const float* __restrict__ b1,
    const float* __restrict__ W2, const float* __restrict__ b2,
    float* __restrict__ out)
{
    const int w = threadIdx.x >> 6;
    const int j = threadIdx.x & 63;
    const long e = (long)blockIdx.x * 4 + w;
    if (e >= N_EDGES) return;
    const int s  = ei[e];
    const int dd = ei[(long)N_EDGES + e];

    float acc = b1[j];
    for (int k = 0; k < 64; ++k) acc += x[(long)s  * 64 + k] * W1[k * 64 + j];
    for (int k = 0; k < 64; ++k) acc += x[(long)dd * 64 + k] * W1[(64 + k) * 64 + j];
    for (int k = 0; k < 16; ++k) acc += edge_attr[e * 16 + k] * W1[(128 + k) * 64 + j];
    const float h = fmaxf(acc, 0.f);

    float msg = b2[j];
    for (int k = 0; k < 64; ++k) msg += __shfl(h, k) * W2[k * 64 + j];
    unsafeAtomicAdd(&out[(long)dd * 64 + j], msg);
}

extern "C" void kernel_launch(void* const* d_in, const int* in_sizes, int n_in,
                              void* d_out, int out_size, void* d_ws, size_t ws_size,
                              hipStream_t stream) {
    const float* x   = (const float*)d_in[0];
    const int*   ei  = (const int*)d_in[1];
    const float* ea  = (const float*)d_in[2];
    const float* W1  = (const float*)d_in[3];
    const float* b1  = (const float*)d_in[4];
    const float* W2  = (const float*)d_in[5];
    const float* b2  = (const float*)d_in[6];
    float* out = (float*)d_out;

    const size_t NF = (size_t)N_NODES * 64;
    const size_t need_main = 2 * NF * 4                    // xa, xb
                           + (size_t)N_NODES * 4           // cnt
                           + 2048 + 256                    // bcnt(512 u32), ocnt
                           + (size_t)NBINS * BINCAP * 4    // bins
                           + (size_t)N_NODES * CAP * 4     // slot (edge id)
                           + (size_t)N_EDGES * 4;          // oflow
    const size_t need_old = 2 * NF * 4;

    if (ws_size >= need_main) {
        char* p = (char*)d_ws;
        float*    xauf  = (float*)p;    p += NF * 4;
        float*    xbuf  = (float*)p;    p += NF * 4;
        unsigned* cnt   = (unsigned*)p; p += (size_t)N_NODES * 4;
        unsigned* bcnt  = (unsigned*)p; p += 2048;          // 512 u32 (391 used)
        unsigned* ocnt  = (unsigned*)p; p += 256;
        unsigned* bins  = (unsigned*)p; p += (size_t)NBINS * BINCAP * 4;
        unsigned* slot  = (unsigned*)p; p += (size_t)N_NODES * CAP * 4;
        unsigned* oflow = (unsigned*)p;

        hipMemsetAsync(bcnt, 0, 2048 + 256, stream);   // bcnt + ocnt only
        prebuild_kernel<<<PB_BLOCKS, 256, 0, stream>>>(
            x, W1, xauf, xbuf, ei, bcnt, ocnt, bins, oflow);
        bucketize_kernel<<<NBINS, 256, 0, stream>>>(
            bins, bcnt, cnt, slot, ocnt, oflow);
        nodefused_kernel<<<N_NODES / 4, 256, 0, stream>>>(
            xauf, xbuf, ea, slot, ei, cnt, W1, b1, W2, b2, out);
        overflow_kernel<<<16, 256, 0, stream>>>(xauf, xbuf, ei, ea, W1, b1,
                                                W2, b2, ocnt, oflow, out);
    } else if (ws_size >= need_old) {
        hipMemsetAsync(out, 0, (size_t)N_NODES * 64 * sizeof(float), stream);
        float* xauf = (float*)d_ws;
        float* xbuf = xauf + NF;
        pre_kernel<<<512, 256, 0, stream>>>(x, W1, xauf, xbuf);
        edge_kernel<<<N_EDGES / 64, 256, 0, stream>>>(xauf, xbuf, ei, ea,
                                                      W1, b1, W2, b2, out);
    } else {
        hipMemsetAsync(out, 0, (size_t)N_NODES * 64 * sizeof(float), stream);
        fallback_kernel<<<N_EDGES / 4, 256, 0, stream>>>(x, ei, ea,
                                                         W1, b1, W2, b2, out);
    }
}

// Round 7
// 274.353 us; speedup vs baseline: 2.8021x; 2.8021x over previous
//
#include <hip/hip_runtime.h>

#define N_NODES 50000
#define N_EDGES 800000
#define CAP 48
#define PB_BLOCKS 2560
#define SHARD_N 6250       // nodes per XCD shard (50000/8)
// IN_F = 64, OUT_F = 64, EDGE_F = 16, d_in1 = 144
// NOTE: harness passes ALL integer inputs as int32 — edge_index is int32[2*E],
// src = ei[e], dst = ei[E+e].
// NOTE (round 3): hipLaunchCooperativeKernel inside kernel_launch broke the
// harness (graph capture) — container failed twice. DO NOT use coop launch.
// NOTE (round 5): direct per-edge scattered slot writes drain at ~740 GB/s
// (partial-line writebacks bouncing across 8 non-coherent L2s) — 111 us.
// NOTE (round 6): two-level binning with 391 global bin counters = atomic
// serialization catastrophe (589 us, VALUBusy 3%). Few hot atomic counters
// are far worse than scattered writes. Keep 50k per-node counters.
// Round 7: XCD-shard the build by dst range so each node's cnt/slot lines
// are written from ONE XCD only (blockIdx%8 == XCD, perf heuristic only —
// partition is (bid%8, dst-range) so correctness never depends on mapping).

#define FMA16(acc, ep, wreg)                                                 \
    {                                                                        \
        float4 _e0 = (ep)[0], _e1 = (ep)[1], _e2 = (ep)[2], _e3 = (ep)[3];   \
        acc += _e0.x * wreg[0];  acc += _e0.y * wreg[1];                     \
        acc += _e0.z * wreg[2];  acc += _e0.w * wreg[3];                     \
        acc += _e1.x * wreg[4];  acc += _e1.y * wreg[5];                     \
        acc += _e1.z * wreg[6];  acc += _e1.w * wreg[7];                     \
        acc += _e2.x * wreg[8];  acc += _e2.y * wreg[9];                     \
        acc += _e2.z * wreg[10]; acc += _e2.w * wreg[11];                    \
        acc += _e3.x * wreg[12]; acc += _e3.y * wreg[13];                    \
        acc += _e3.z * wreg[14]; acc += _e3.w * wreg[15];                    \
    }

// ---------------------------------------------------------------------------
// prebuild_kernel: EVERY block does
//   (1) build chunk (XCD-sharded): shard s = bid&7 takes edges with
//       dst in [s*6250,(s+1)*6250); 320 blocks/shard grid-stride the full
//       edge list with a range filter. All writes to a node's cnt/slot
//       lines come from one XCD -> line fills while L2-resident, evicts once.
//   (2) pre chunk: xa = x @ W1[0:64,:], xb = x @ W1[64:128,:]
// cnt/ocnt must be zeroed before launch (memsetAsync).
// ---------------------------------------------------------------------------
__global__ __launch_bounds__(256) void prebuild_kernel(
    const float* __restrict__ x, const float* __restrict__ W1,
    float* __restrict__ xa, float* __restrict__ xb,
    const int* __restrict__ ei, unsigned* __restrict__ cnt,
    unsigned* __restrict__ ocnt, unsigned* __restrict__ slot,
    unsigned* __restrict__ oflow)
{
    const int tid = threadIdx.x;
    const int bid = blockIdx.x;

    // ---- build part: shard-filtered scan of all edges ----
    {
        const int s = bid & 7;
        const unsigned dlo = (unsigned)s * SHARD_N;
        const unsigned dhi = dlo + SHARD_N;
        const int wb = bid >> 3;                       // 0..319 within shard
        for (int e = wb * 256 + tid; e < N_EDGES; e += (PB_BLOCKS / 8) * 256) {
            const unsigned d = (unsigned)ei[N_EDGES + e];
            if (d >= dlo && d < dhi) {
                const unsigned pos = atomicAdd(&cnt[d], 1u);
                if (pos < CAP) {
                    slot[(size_t)d * CAP + pos] = (unsigned)e;
                } else {
                    const unsigned oi = atomicAdd(ocnt, 1u);
                    oflow[oi] = (unsigned)e;
                }
            }
        }
    }

    // ---- pre part: wave per (node-subset, product) ----
    const int w = tid >> 6;
    const int j = tid & 63;
    const int gw = bid * 4 + w;
    const int p = gw & 1;              // 0 -> xa, 1 -> xb
    const int pair = gw >> 1;
    const int npair = PB_BLOCKS * 2;   // 5120

    float wc[64];
#pragma unroll
    for (int k = 0; k < 64; ++k) wc[k] = W1[(p * 64 + k) * 64 + j];
    float* __restrict__ outp = p ? xb : xa;
    for (int i = pair; i < N_NODES; i += npair) {
        const float4* xr = (const float4*)&x[(size_t)i * 64];
        float acc = 0.f;
#pragma unroll
        for (int k4 = 0; k4 < 16; ++k4) {
            float4 xv = xr[k4];
            acc += xv.x * wc[k4 * 4 + 0];
            acc += xv.y * wc[k4 * 4 + 1];
            acc += xv.z * wc[k4 * 4 + 2];
            acc += xv.w * wc[k4 * 4 + 3];
        }
        outp[(size_t)i * 64 + j] = acc;
    }
}

// ---------------------------------------------------------------------------
// nodefused_kernel: one wave per dst node.  (UNCHANGED from round 5)
//   hacc = sum_e relu(xa[src]+xb[n]+ea@W1c+b1)    (aggregation)
//   out[n] = hacc @ W2 + dcap*b2                  (W2 hoisted out of seg-sum)
// ---------------------------------------------------------------------------
__global__ __launch_bounds__(256) void nodefused_kernel(
    const float* __restrict__ xa, const float* __restrict__ xb,
    const float* __restrict__ ea, const unsigned* __restrict__ slot,
    const int* __restrict__ ei, const unsigned* __restrict__ cnt,
    const float* __restrict__ W1, const float* __restrict__ b1,
    const float* __restrict__ W2, const float* __restrict__ b2,
    float* __restrict__ out)
{
    __shared__ __align__(16) float sea[4][CAP * 16];   // 12 KB / block

    const int w = threadIdx.x >> 6;
    const int j = threadIdx.x & 63;
    const int n = blockIdx.x * 4 + w;

    float w1c[16];
#pragma unroll
    for (int k = 0; k < 16; ++k) w1c[k] = W1[(128 + k) * 64 + j];
    const float b1j = b1[j];
    const float b2j = b2[j];

    const int deg = (int)cnt[n];
    const int dcap = deg < CAP ? deg : CAP;

    int ev = 0, sv = 0;
    if (j < dcap) {
        ev = (int)slot[(size_t)n * CAP + j];
        sv = ei[ev];
    }

    const float base = xb[(size_t)n * 64 + j] + b1j;

    float hacc = 0.f;
    if (dcap > 0) {
        const int sub = j >> 2;
        const int q   = j & 3;

        for (int b0 = 0; b0 < dcap; b0 += 16) {
            {
                int ii = b0 + sub;
                const int ic = ii < dcap ? ii : dcap - 1;
                const unsigned eid = (unsigned)__shfl(ev, ic);
                float4 v = *(const float4*)(ea + (size_t)eid * 16 + q * 4);
                *(float4*)&sea[w][ic * 16 + q * 4] = v;
            }
            float xv[16];
#pragma unroll
            for (int t = 0; t < 16; ++t) {
                int ii = b0 + t;
                const int ic = ii < dcap ? ii : dcap - 1;
                const unsigned ss =
                    (unsigned)__builtin_amdgcn_readlane(sv, ic);
                xv[t] = xa[(size_t)ss * 64 + j];
            }
#pragma unroll
            for (int t = 0; t < 16; ++t) {
                const int ii = b0 + t;
                if (ii < dcap) {
                    const float4* ep = (const float4*)&sea[w][ii * 16];
                    float acc = base + xv[t];
                    FMA16(acc, ep, w1c);
                    hacc += fmaxf(acc, 0.f);
                }
            }
        }
    }

    sea[w][j] = hacc;
    float msg = (float)dcap * b2j;
#pragma unroll
    for (int k4 = 0; k4 < 16; ++k4) {
        float4 hv = *(const float4*)&sea[w][k4 * 4];
        msg += hv.x * W2[(k4 * 4 + 0) * 64 + j];
        msg += hv.y * W2[(k4 * 4 + 1) * 64 + j];
        msg += hv.z * W2[(k4 * 4 + 2) * 64 + j];
        msg += hv.w * W2[(k4 * 4 + 3) * 64 + j];
    }
    out[(size_t)n * 64 + j] = msg;
}

// ---------------------------------------------------------------------------
// overflow_kernel: correctness net (expected 0 edges). Runs AFTER nodefused.
// ---------------------------------------------------------------------------
__global__ __launch_bounds__(256) void overflow_kernel(
    const float* __restrict__ xa, const float* __restrict__ xb,
    const int* __restrict__ ei, const float* __restrict__ ea,
    const float* __restrict__ W1, const float* __restrict__ b1,
    const float* __restrict__ W2, const float* __restrict__ b2,
    const unsigned* __restrict__ ocnt, const unsigned* __restrict__ oflow,
    float* __restrict__ out)
{
    const unsigned oc = *ocnt;
    if (oc == 0) return;
    const int w = threadIdx.x >> 6;
    const int j = threadIdx.x & 63;
    unsigned idx = blockIdx.x * 4 + w;
    const unsigned stride = gridDim.x * 4;
    for (; idx < oc; idx += stride) {
        const int e = (int)oflow[idx];
        const int s = ei[e];
        const int dd = ei[N_EDGES + e];
        float acc = xa[(size_t)s * 64 + j] + xb[(size_t)dd * 64 + j] + b1[j];
        for (int k = 0; k < 16; ++k)
            acc += ea[(size_t)e * 16 + k] * W1[(128 + k) * 64 + j];
        const float h = fmaxf(acc, 0.f);
        float msg = b2[j];
        for (int k = 0; k < 64; ++k) msg += __shfl(h, k) * W2[k * 64 + j];
        unsafeAtomicAdd(&out[(size_t)dd * 64 + j], msg);
    }
}

// ---------------------------------------------------------------------------
// OLD PATH kernels (ws too small for bucketed pipeline)
// ---------------------------------------------------------------------------
__global__ __launch_bounds__(256) void pre_kernel(
    const float* __restrict__ x, const float* __restrict__ W1,
    float* __restrict__ xa, float* __restrict__ xb)
{
    const int w = threadIdx.x >> 6;
    const int j = threadIdx.x & 63;
    const int gw = blockIdx.x * 4 + w;
    const int p = gw & 1;
    const int pair = gw >> 1;
    const int npair = (gridDim.x * 4) >> 1;

    float wc[64];
#pragma unroll
    for (int k = 0; k < 64; ++k) wc[k] = W1[(p * 64 + k) * 64 + j];
    float* __restrict__ outp = p ? xb : xa;
    for (int i = pair; i < N_NODES; i += npair) {
        const float4* xr = (const float4*)&x[(size_t)i * 64];
        float acc = 0.f;
#pragma unroll
        for (int k4 = 0; k4 < 16; ++k4) {
            float4 xv = xr[k4];
            acc += xv.x * wc[k4 * 4 + 0];
            acc += xv.y * wc[k4 * 4 + 1];
            acc += xv.z * wc[k4 * 4 + 2];
            acc += xv.w * wc[k4 * 4 + 3];
        }
        outp[(size_t)i * 64 + j] = acc;
    }
}

__global__ __launch_bounds__(256) void edge_kernel(
    const float* __restrict__ xa, const float* __restrict__ xb,
    const int* __restrict__ ei,
    const float* __restrict__ edge_attr,
    const float* __restrict__ W1, const float* __restrict__ b1,
    const float* __restrict__ W2, const float* __restrict__ b2,
    float* __restrict__ out)
{
    __shared__ __align__(16) float eas[4][256];
    __shared__ __align__(16) float hs[4][16][64];

    const int w = threadIdx.x >> 6;
    const int j = threadIdx.x & 63;
    const int wt = blockIdx.x * 4 + w;
    const long eb = (long)wt * 16;

    float w1c[16];
    float w2c[64];
#pragma unroll
    for (int k = 0; k < 16; ++k) w1c[k] = W1[(128 + k) * 64 + j];
#pragma unroll
    for (int k = 0; k < 64; ++k) w2c[k] = W2[k * 64 + j];
    const float b1j = b1[j];
    const float b2j = b2[j];

    int idxv = 0;
    if (j < 16)       idxv = ei[eb + j];
    else if (j < 32)  idxv = ei[(long)N_EDGES + eb + (j - 16)];

    {
        float4 ev = *(const float4*)&edge_attr[eb * 16 + j * 4];
        *(float4*)&eas[w][j * 4] = ev;
    }

#pragma unroll 4
    for (int e = 0; e < 16; ++e) {
        const int s  = __shfl(idxv, e);
        const int dd = __shfl(idxv, 16 + e);

        float acc = xa[(long)s * 64 + j] + xb[(long)dd * 64 + j] + b1j;
#pragma unroll
        for (int k4 = 0; k4 < 4; ++k4) {
            float4 ev = *(const float4*)&eas[w][e * 16 + k4 * 4];
            acc += ev.x * w1c[k4 * 4 + 0];
            acc += ev.y * w1c[k4 * 4 + 1];
            acc += ev.z * w1c[k4 * 4 + 2];
            acc += ev.w * w1c[k4 * 4 + 3];
        }
        const float h = fmaxf(acc, 0.f);
        hs[w][e][j] = h;

        float msg = b2j;
#pragma unroll
        for (int k4 = 0; k4 < 16; ++k4) {
            float4 hv = *(const float4*)&hs[w][e][k4 * 4];
            msg += hv.x * w2c[k4 * 4 + 0];
            msg += hv.y * w2c[k4 * 4 + 1];
            msg += hv.z * w2c[k4 * 4 + 2];
            msg += hv.w * w2c[k4 * 4 + 3];
        }
        unsafeAtomicAdd(&out[(long)dd * 64 + j], msg);
    }
}

__global__ __launch_bounds__(256) void fallback_kernel(
    const float* __restrict__ x, const int* __restrict__ ei,
    const float* __restrict__ edge_attr,
    const float* __restrict__ W1, const float* __restrict__ b1,
    const float* __restrict__ W2, const float* __restrict__ b2,
    float* __restrict__ out)
{
    const int w = threadIdx.x >> 6;
    const int j = threadIdx.x & 63;
    const long e = (long)blockIdx.x * 4 + w;
    if (e >= N_EDGES) return;
    const int s  = ei[e];
    const int dd = ei[(long)N_EDGES + e];

    float acc = b1[j];
    for (int k = 0; k < 64; ++k) acc += x[(long)s  * 64 + k] * W1[k * 64 + j];
    for (int k = 0; k < 64; ++k) acc += x[(long)dd * 64 + k] * W1[(64 + k) * 64 + j];
    for (int k = 0; k < 16; ++k) acc += edge_attr[e * 16 + k] * W1[(128 + k) * 64 + j];
    const float h = fmaxf(acc, 0.f);

    float msg = b2[j];
    for (int k = 0; k < 64; ++k) msg += __shfl(h, k) * W2[k * 64 + j];
    unsafeAtomicAdd(&out[(long)dd * 64 + j], msg);
}

extern "C" void kernel_launch(void* const* d_in, const int* in_sizes, int n_in,
                              void* d_out, int out_size, void* d_ws, size_t ws_size,
                              hipStream_t stream) {
    const float* x   = (const float*)d_in[0];
    const int*   ei  = (const int*)d_in[1];
    const float* ea  = (const float*)d_in[2];
    const float* W1  = (const float*)d_in[3];
    const float* b1  = (const float*)d_in[4];
    const float* W2  = (const float*)d_in[5];
    const float* b2  = (const float*)d_in[6];
    float* out = (float*)d_out;

    const size_t NF = (size_t)N_NODES * 64;
    const size_t need_main = 2 * NF * 4                    // xa, xb
                           + (size_t)N_NODES * 4 + 256     // cnt, ocnt(+pad)
                           + (size_t)N_NODES * CAP * 4     // slot (edge id)
                           + (size_t)N_EDGES * 4;          // oflow
    const size_t need_old = 2 * NF * 4;

    if (ws_size >= need_main) {
        char* p = (char*)d_ws;
        float*    xauf  = (float*)p;    p += NF * 4;
        float*    xbuf  = (float*)p;    p += NF * 4;
        unsigned* cnt   = (unsigned*)p; p += (size_t)N_NODES * 4;
        unsigned* ocnt  = (unsigned*)p; p += 256;
        unsigned* slot  = (unsigned*)p; p += (size_t)N_NODES * CAP * 4;
        unsigned* oflow = (unsigned*)p;

        hipMemsetAsync(cnt, 0, (size_t)N_NODES * 4 + 256, stream);
        prebuild_kernel<<<PB_BLOCKS, 256, 0, stream>>>(
            x, W1, xauf, xbuf, ei, cnt, ocnt, slot, oflow);
        nodefused_kernel<<<N_NODES / 4, 256, 0, stream>>>(
            xauf, xbuf, ea, slot, ei, cnt, W1, b1, W2, b2, out);
        overflow_kernel<<<16, 256, 0, stream>>>(xauf, xbuf, ei, ea, W1, b1,
                                                W2, b2, ocnt, oflow, out);
    } else if (ws_size >= need_old) {
        hipMemsetAsync(out, 0, (size_t)N_NODES * 64 * sizeof(float), stream);
        float* xauf = (float*)d_ws;
        float* xbuf = xauf + NF;
        pre_kernel<<<512, 256, 0, stream>>>(x, W1, xauf, xbuf);
        edge_kernel<<<N_EDGES / 64, 256, 0, stream>>>(xauf, xbuf, ei, ea,
                                                      W1, b1, W2, b2, out);
    } else {
        hipMemsetAsync(out, 0, (size_t)N_NODES * 64 * sizeof(float), stream);
        fallback_kernel<<<N_EDGES / 4, 256, 0, stream>>>(x, ei, ea,
                                                         W1, b1, W2, b2, out);
    }
}

// Round 8
// 233.965 us; speedup vs baseline: 3.2858x; 1.1726x over previous
//
#include <hip/hip_runtime.h>

#define N_NODES 50000
#define N_EDGES 800000
#define CAP 48
#define PB_BLOCKS 2560
// IN_F = 64, OUT_F = 64, EDGE_F = 16, d_in1 = 144
// NOTE: harness passes ALL integer inputs as int32 — edge_index is int32[2*E],
// src = ei[e], dst = ei[E+e].
// NOTE (round 3): hipLaunchCooperativeKernel inside kernel_launch broke the
// harness (graph capture) — container failed twice. DO NOT use coop launch.
// NOTE (round 6): two-level binning with 391 global bin counters = atomic
// serialization catastrophe (589 us, VALUBusy 3%). Keep 50k per-node counters.
// NOTE (rounds 5+7): scattered slot writes / atomic locality are NOT the
// prebuild bottleneck (WRITE 72.5->57.8 MB changed nothing). The ~110 us is
// the pre-GEMM's 16 wave-uniform float4 x-loads per node: wc[64] leaves no
// landing VGPRs, loads issue in small vmcnt-waited groups -> ~2400 cyc/node
// serial latency. Round 8 fixes the load path: per-lane coalesced load ->
// LDS row -> broadcast ds_read_b128 consumption (proven nodefused pattern).

#define FMA16(acc, ep, wreg)                                                 \
    {                                                                        \
        float4 _e0 = (ep)[0], _e1 = (ep)[1], _e2 = (ep)[2], _e3 = (ep)[3];   \
        acc += _e0.x * wreg[0];  acc += _e0.y * wreg[1];                     \
        acc += _e0.z * wreg[2];  acc += _e0.w * wreg[3];                     \
        acc += _e1.x * wreg[4];  acc += _e1.y * wreg[5];                     \
        acc += _e1.z * wreg[6];  acc += _e1.w * wreg[7];                     \
        acc += _e2.x * wreg[8];  acc += _e2.y * wreg[9];                     \
        acc += _e2.z * wreg[10]; acc += _e2.w * wreg[11];                    \
        acc += _e3.x * wreg[12]; acc += _e3.y * wreg[13];                    \
        acc += _e3.z * wreg[14]; acc += _e3.w * wreg[15];                    \
    }

// ---------------------------------------------------------------------------
// prebuild_kernel: EVERY block does
//   (1) build chunk: grid-stride over edges, bucket e by dst (round-5 style)
//   (2) pre chunk: xa = x @ W1[0:64,:], xb = x @ W1[64:128,:]
//       x row path: per-lane coalesced load -> per-wave LDS row -> 16
//       broadcast ds_read_b128; next-row load software-pipelined; 4 partial
//       accumulator chains for ILP. One in-flight global load per iteration.
// cnt/ocnt must be zeroed before launch (memsetAsync).
// ---------------------------------------------------------------------------
__global__ __launch_bounds__(256) void prebuild_kernel(
    const float* __restrict__ x, const float* __restrict__ W1,
    float* __restrict__ xa, float* __restrict__ xb,
    const int* __restrict__ ei, unsigned* __restrict__ cnt,
    unsigned* __restrict__ ocnt, unsigned* __restrict__ slot,
    unsigned* __restrict__ oflow)
{
    __shared__ __align__(16) float srow[4][64];   // per-wave x-row buffer

    const int tid = threadIdx.x;
    const int bid = blockIdx.x;

    // ---- build part: bucket edges by dst (store edge id only, 4 B) ----
    for (int e = bid * 256 + tid; e < N_EDGES; e += PB_BLOCKS * 256) {
        const int d = ei[N_EDGES + e];
        const unsigned pos = atomicAdd(&cnt[d], 1u);
        if (pos < CAP) {
            slot[(size_t)d * CAP + pos] = (unsigned)e;
        } else {
            const unsigned oi = atomicAdd(ocnt, 1u);
            oflow[oi] = (unsigned)e;
        }
    }

    // ---- pre part: wave per (node-subset, product) ----
    const int w = tid >> 6;
    const int j = tid & 63;
    const int gw = bid * 4 + w;
    const int p = gw & 1;              // 0 -> xa, 1 -> xb
    const int pair = gw >> 1;
    const int npair = PB_BLOCKS * 2;   // 5120

    float wc[64];
#pragma unroll
    for (int k = 0; k < 64; ++k) wc[k] = W1[(p * 64 + k) * 64 + j];
    float* __restrict__ outp = p ? xb : xa;

    if (pair < N_NODES) {
        float xv = x[(size_t)pair * 64 + j];          // pipelined row element
        for (int i = pair; i < N_NODES; i += npair) {
            srow[w][j] = xv;                           // wave-internal LDS write
            const int inext = i + npair;
            float xnext = 0.f;
            if (inext < N_NODES) xnext = x[(size_t)inext * 64 + j];

            float a0 = 0.f, a1 = 0.f, a2 = 0.f, a3 = 0.f;
#pragma unroll
            for (int k4 = 0; k4 < 4; ++k4) {
                const float4 v0 = *(const float4*)&srow[w][k4 * 16 + 0];
                const float4 v1 = *(const float4*)&srow[w][k4 * 16 + 4];
                const float4 v2 = *(const float4*)&srow[w][k4 * 16 + 8];
                const float4 v3 = *(const float4*)&srow[w][k4 * 16 + 12];
                a0 += v0.x * wc[k4 * 16 + 0];  a0 += v0.y * wc[k4 * 16 + 1];
                a0 += v0.z * wc[k4 * 16 + 2];  a0 += v0.w * wc[k4 * 16 + 3];
                a1 += v1.x * wc[k4 * 16 + 4];  a1 += v1.y * wc[k4 * 16 + 5];
                a1 += v1.z * wc[k4 * 16 + 6];  a1 += v1.w * wc[k4 * 16 + 7];
                a2 += v2.x * wc[k4 * 16 + 8];  a2 += v2.y * wc[k4 * 16 + 9];
                a2 += v2.z * wc[k4 * 16 + 10]; a2 += v2.w * wc[k4 * 16 + 11];
                a3 += v3.x * wc[k4 * 16 + 12]; a3 += v3.y * wc[k4 * 16 + 13];
                a3 += v3.z * wc[k4 * 16 + 14]; a3 += v3.w * wc[k4 * 16 + 15];
            }
            outp[(size_t)i * 64 + j] = (a0 + a1) + (a2 + a3);
            xv = xnext;
        }
    }
}

// ---------------------------------------------------------------------------
// nodefused_kernel: one wave per dst node.  (UNCHANGED from round 5)
//   hacc = sum_e relu(xa[src]+xb[n]+ea@W1c+b1)    (aggregation)
//   out[n] = hacc @ W2 + dcap*b2                  (W2 hoisted out of seg-sum)
// ---------------------------------------------------------------------------
__global__ __launch_bounds__(256) void nodefused_kernel(
    const float* __restrict__ xa, const float* __restrict__ xb,
    const float* __restrict__ ea, const unsigned* __restrict__ slot,
    const int* __restrict__ ei, const unsigned* __restrict__ cnt,
    const float* __restrict__ W1, const float* __restrict__ b1,
    const float* __restrict__ W2, const float* __restrict__ b2,
    float* __restrict__ out)
{
    __shared__ __align__(16) float sea[4][CAP * 16];   // 12 KB / block

    const int w = threadIdx.x >> 6;
    const int j = threadIdx.x & 63;
    const int n = blockIdx.x * 4 + w;

    float w1c[16];
#pragma unroll
    for (int k = 0; k < 16; ++k) w1c[k] = W1[(128 + k) * 64 + j];
    const float b1j = b1[j];
    const float b2j = b2[j];

    const int deg = (int)cnt[n];
    const int dcap = deg < CAP ? deg : CAP;

    int ev = 0, sv = 0;
    if (j < dcap) {
        ev = (int)slot[(size_t)n * CAP + j];
        sv = ei[ev];
    }

    const float base = xb[(size_t)n * 64 + j] + b1j;

    float hacc = 0.f;
    if (dcap > 0) {
        const int sub = j >> 2;
        const int q   = j & 3;

        for (int b0 = 0; b0 < dcap; b0 += 16) {
            {
                int ii = b0 + sub;
                const int ic = ii < dcap ? ii : dcap - 1;
                const unsigned eid = (unsigned)__shfl(ev, ic);
                float4 v = *(const float4*)(ea + (size_t)eid * 16 + q * 4);
                *(float4*)&sea[w][ic * 16 + q * 4] = v;
            }
            float xv[16];
#pragma unroll
            for (int t = 0; t < 16; ++t) {
                int ii = b0 + t;
                const int ic = ii < dcap ? ii : dcap - 1;
                const unsigned ss =
                    (unsigned)__builtin_amdgcn_readlane(sv, ic);
                xv[t] = xa[(size_t)ss * 64 + j];
            }
#pragma unroll
            for (int t = 0; t < 16; ++t) {
                const int ii = b0 + t;
                if (ii < dcap) {
                    const float4* ep = (const float4*)&sea[w][ii * 16];
                    float acc = base + xv[t];
                    FMA16(acc, ep, w1c);
                    hacc += fmaxf(acc, 0.f);
                }
            }
        }
    }

    sea[w][j] = hacc;
    float msg = (float)dcap * b2j;
#pragma unroll
    for (int k4 = 0; k4 < 16; ++k4) {
        float4 hv = *(const float4*)&sea[w][k4 * 4];
        msg += hv.x * W2[(k4 * 4 + 0) * 64 + j];
        msg += hv.y * W2[(k4 * 4 + 1) * 64 + j];
        msg += hv.z * W2[(k4 * 4 + 2) * 64 + j];
        msg += hv.w * W2[(k4 * 4 + 3) * 64 + j];
    }
    out[(size_t)n * 64 + j] = msg;
}

// ---------------------------------------------------------------------------
// overflow_kernel: correctness net (expected 0 edges). Runs AFTER nodefused.
// ---------------------------------------------------------------------------
__global__ __launch_bounds__(256) void overflow_kernel(
    const float* __restrict__ xa, const float* __restrict__ xb,
    const int* __restrict__ ei, const float* __restrict__ ea,
    const float* __restrict__ W1, const float* __restrict__ b1,
    const float* __restrict__ W2, const float* __restrict__ b2,
    const unsigned* __restrict__ ocnt, const unsigned* __restrict__ oflow,
    float* __restrict__ out)
{
    const unsigned oc = *ocnt;
    if (oc == 0) return;
    const int w = threadIdx.x >> 6;
    const int j = threadIdx.x & 63;
    unsigned idx = blockIdx.x * 4 + w;
    const unsigned stride = gridDim.x * 4;
    for (; idx < oc; idx += stride) {
        const int e = (int)oflow[idx];
        const int s = ei[e];
        const int dd = ei[N_EDGES + e];
        float acc = xa[(size_t)s * 64 + j] + xb[(size_t)dd * 64 + j] + b1[j];
        for (int k = 0; k < 16; ++k)
            acc += ea[(size_t)e * 16 + k] * W1[(128 + k) * 64 + j];
        const float h = fmaxf(acc, 0.f);
        float msg = b2[j];
        for (int k = 0; k < 64; ++k) msg += __shfl(h, k) * W2[k * 64 + j];
        unsafeAtomicAdd(&out[(size_t)dd * 64 + j], msg);
    }
}

// ---------------------------------------------------------------------------
// OLD PATH kernels (ws too small for bucketed pipeline)
// ---------------------------------------------------------------------------
__global__ __launch_bounds__(256) void pre_kernel(
    const float* __restrict__ x, const float* __restrict__ W1,
    float* __restrict__ xa, float* __restrict__ xb)
{
    const int w = threadIdx.x >> 6;
    const int j = threadIdx.x & 63;
    const int gw = blockIdx.x * 4 + w;
    const int p = gw & 1;
    const int pair = gw >> 1;
    const int npair = (gridDim.x * 4) >> 1;

    float wc[64];
#pragma unroll
    for (int k = 0; k < 64; ++k) wc[k] = W1[(p * 64 + k) * 64 + j];
    float* __restrict__ outp = p ? xb : xa;
    for (int i = pair; i < N_NODES; i += npair) {
        const float4* xr = (const float4*)&x[(size_t)i * 64];
        float acc = 0.f;
#pragma unroll
        for (int k4 = 0; k4 < 16; ++k4) {
            float4 xv = xr[k4];
            acc += xv.x * wc[k4 * 4 + 0];
            acc += xv.y * wc[k4 * 4 + 1];
            acc += xv.z * wc[k4 * 4 + 2];
            acc += xv.w * wc[k4 * 4 + 3];
        }
        outp[(size_t)i * 64 + j] = acc;
    }
}

__global__ __launch_bounds__(256) void edge_kernel(
    const float* __restrict__ xa, const float* __restrict__ xb,
    const int* __restrict__ ei,
    const float* __restrict__ edge_attr,
    const float* __restrict__ W1, const float* __restrict__ b1,
    const float* __restrict__ W2, const float* __restrict__ b2,
    float* __restrict__ out)
{
    __shared__ __align__(16) float eas[4][256];
    __shared__ __align__(16) float hs[4][16][64];

    const int w = threadIdx.x >> 6;
    const int j = threadIdx.x & 63;
    const int wt = blockIdx.x * 4 + w;
    const long eb = (long)wt * 16;

    float w1c[16];
    float w2c[64];
#pragma unroll
    for (int k = 0; k < 16; ++k) w1c[k] = W1[(128 + k) * 64 + j];
#pragma unroll
    for (int k = 0; k < 64; ++k) w2c[k] = W2[k * 64 + j];
    const float b1j = b1[j];
    const float b2j = b2[j];

    int idxv = 0;
    if (j < 16)       idxv = ei[eb + j];
    else if (j < 32)  idxv = ei[(long)N_EDGES + eb + (j - 16)];

    {
        float4 ev = *(const float4*)&edge_attr[eb * 16 + j * 4];
        *(float4*)&eas[w][j * 4] = ev;
    }

#pragma unroll 4
    for (int e = 0; e < 16; ++e) {
        const int s  = __shfl(idxv, e);
        const int dd = __shfl(idxv, 16 + e);

        float acc = xa[(long)s * 64 + j] + xb[(long)dd * 64 + j] + b1j;
#pragma unroll
        for (int k4 = 0; k4 < 4; ++k4) {
            float4 ev = *(const float4*)&eas[w][e * 16 + k4 * 4];
            acc += ev.x * w1c[k4 * 4 + 0];
            acc += ev.y * w1c[k4 * 4 + 1];
            acc += ev.z * w1c[k4 * 4 + 2];
            acc += ev.w * w1c[k4 * 4 + 3];
        }
        const float h = fmaxf(acc, 0.f);
        hs[w][e][j] = h;

        float msg = b2j;
#pragma unroll
        for (int k4 = 0; k4 < 16; ++k4) {
            float4 hv = *(const float4*)&hs[w][e][k4 * 4];
            msg += hv.x * w2c[k4 * 4 + 0];
            msg += hv.y * w2c[k4 * 4 + 1];
            msg += hv.z * w2c[k4 * 4 + 2];
            msg += hv.w * w2c[k4 * 4 + 3];
        }
        unsafeAtomicAdd(&out[(long)dd * 64 + j], msg);
    }
}

__global__ __launch_bounds__(256) void fallback_kernel(
    const float* __restrict__ x, const int* __restrict__ ei,
    const float* __restrict__ edge_attr,
    const float* __restrict__ W1, const float* __restrict__ b1,
    const float* __restrict__ W2, const float* __restrict__ b2,
    float* __restrict__ out)
{
    const int w = threadIdx.x >> 6;
    const int j = threadIdx.x & 63;
    const long e = (long)blockIdx.x * 4 + w;
    if (e >= N_EDGES) return;
    const int s  = ei[e];
    const int dd = ei[(long)N_EDGES + e];

    float acc = b1[j];
    for (int k = 0; k < 64; ++k) acc += x[(long)s  * 64 + k] * W1[k * 64 + j];
    for (int k = 0; k < 64; ++k) acc += x[(long)dd * 64 + k] * W1[(64 + k) * 64 + j];
    for (int k = 0; k < 16; ++k) acc += edge_attr[e * 16 + k] * W1[(128 + k) * 64 + j];
    const float h = fmaxf(acc, 0.f);

    float msg = b2[j];
    for (int k = 0; k < 64; ++k) msg += __shfl(h, k) * W2[k * 64 + j];
    unsafeAtomicAdd(&out[(long)dd * 64 + j], msg);
}

extern "C" void kernel_launch(void* const* d_in, const int* in_sizes, int n_in,
                              void* d_out, int out_size, void* d_ws, size_t ws_size,
                              hipStream_t stream) {
    const float* x   = (const float*)d_in[0];
    const int*   ei  = (const int*)d_in[1];
    const float* ea  = (const float*)d_in[2];
    const float* W1  = (const float*)d_in[3];
    const float* b1  = (const float*)d_in[4];
    const float* W2  = (const float*)d_in[5];
    const float* b2  = (const float*)d_in[6];
    float* out = (float*)d_out;

    const size_t NF = (size_t)N_NODES * 64;
    const size_t need_main = 2 * NF * 4                    // xa, xb
                           + (size_t)N_NODES * 4 + 256     // cnt, ocnt(+pad)
                           + (size_t)N_NODES * CAP * 4     // slot (edge id)
                           + (size_t)N_EDGES * 4;          // oflow
    const size_t need_old = 2 * NF * 4;

    if (ws_size >= need_main) {
        char* p = (char*)d_ws;
        float*    xauf  = (float*)p;    p += NF * 4;
        float*    xbuf  = (float*)p;    p += NF * 4;
        unsigned* cnt   = (unsigned*)p; p += (size_t)N_NODES * 4;
        unsigned* ocnt  = (unsigned*)p; p += 256;
        unsigned* slot  = (unsigned*)p; p += (size_t)N_NODES * CAP * 4;
        unsigned* oflow = (unsigned*)p;

        hipMemsetAsync(cnt, 0, (size_t)N_NODES * 4 + 256, stream);
        prebuild_kernel<<<PB_BLOCKS, 256, 0, stream>>>(
            x, W1, xauf, xbuf, ei, cnt, ocnt, slot, oflow);
        nodefused_kernel<<<N_NODES / 4, 256, 0, stream>>>(
            xauf, xbuf, ea, slot, ei, cnt, W1, b1, W2, b2, out);
        overflow_kernel<<<16, 256, 0, stream>>>(xauf, xbuf, ei, ea, W1, b1,
                                                W2, b2, ocnt, oflow, out);
    } else if (ws_size >= need_old) {
        hipMemsetAsync(out, 0, (size_t)N_NODES * 64 * sizeof(float), stream);
        float* xauf = (float*)d_ws;
        float* xbuf = xauf + NF;
        pre_kernel<<<512, 256, 0, stream>>>(x, W1, xauf, xbuf);
        edge_kernel<<<N_EDGES / 64, 256, 0, stream>>>(xauf, xbuf, ei, ea,
                                                      W1, b1, W2, b2, out);
    } else {
        hipMemsetAsync(out, 0, (size_t)N_NODES * 64 * sizeof(float), stream);
        fallback_kernel<<<N_EDGES / 4, 256, 0, stream>>>(x, ei, ea,
                                                         W1, b1, W2, b2, out);
    }
}